// Round 5
// baseline (189.177 us; speedup 1.0000x reference)
//
#include <hip/hip_runtime.h>

// VectorQuantizer: z [32,2048,64] f32, codebook [1024,64] f32.
// out = concat( z_q [4194304], c_loss [1], cb_loss [1] ); c_loss==cb_loss (BETA=1).
//
// R5: R4 counter VGPR=48 proved aA[4][2] (32 VGPR) was rematerialized inside the
// chunk loop (z re-load + 64 reconverts x16 iters -> VALUBusy 21%, MfmaUtil 6%).
// Fix: asm pin on aA (same as R3's fr pin). Also: argmin via index-embedded
// v_min_f32 (3 VALU/pair, no bestk regs), and one-chunk-ahead B/csq prefetch.
// Distance GEMM on bf16 MFMA; gather/z_q/losses exact fp32.

#define VQ_NTOK   65536
#define VQ_D      64
#define VQ_K      1024
#define VQ_NELEM  (VQ_NTOK * VQ_D)

typedef short bf16x8 __attribute__((ext_vector_type(8)));
typedef float f32x4  __attribute__((ext_vector_type(4)));

#define WS_CSQ       0        // 1024 floats: ||c_k||^2
#define WS_LOSS      1024     // 1 float: loss accumulator
#define WS_CBB_BYTES 8192     // byte offset: 128 KB fragment-ordered bf16 codebook

__device__ __forceinline__ short bf16rn(float x) {   // round-to-nearest-even
    unsigned u = __builtin_bit_cast(unsigned, x);
    u += 0x7fffu + ((u >> 16) & 1u);
    return (short)(u >> 16);
}

// grid 32 x 256: csq + loss-zero + bf16 fragment-ordered codebook.
// Element (chunk c, half h, lane L, j) = cb[c*16+(L&15)][h*32+(L>>4)*8+j]
__global__ __launch_bounds__(256) void vq_prep(const float* __restrict__ cb,
                                               float* __restrict__ ws) {
    int t = blockIdx.x * 256 + threadIdx.x;   // 0..8191
    if (t == 0) ws[WS_LOSS] = 0.0f;           // ws re-poisoned every launch
    if (t < VQ_K) {
        const float4* row = (const float4*)(cb + t * VQ_D);
        float s = 0.f;
        #pragma unroll
        for (int j = 0; j < 16; ++j) {
            float4 c = row[j];
            s += c.x * c.x + c.y * c.y + c.z * c.z + c.w * c.w;
        }
        ws[WS_CSQ + t] = s;
    }
    int c = t >> 7, h = (t >> 6) & 1, L = t & 63;
    int k  = c * 16 + (L & 15);
    int d0 = h * 32 + ((L >> 4) << 3);
    const float4* p = (const float4*)(cb + k * VQ_D + d0);
    float4 x0 = p[0], x1 = p[1];
    bf16x8 v;
    v[0] = bf16rn(x0.x); v[1] = bf16rn(x0.y); v[2] = bf16rn(x0.z); v[3] = bf16rn(x0.w);
    v[4] = bf16rn(x1.x); v[5] = bf16rn(x1.y); v[6] = bf16rn(x1.z); v[7] = bf16rn(x1.w);
    bf16x8* cbb = (bf16x8*)((char*)ws + WS_CBB_BYTES);
    cbb[(c * 2 + h) * 64 + L] = v;
}

__global__ __launch_bounds__(256, 4) void vq_mfma(
        const float* __restrict__ z, const float* __restrict__ cb,
        float* __restrict__ ws, float* __restrict__ out) {
    const int tid  = threadIdx.x;
    const int lane = tid & 63;
    const int wave = tid >> 6;         // k-split: wave w scans codes [w*256,(w+1)*256)
    const int m    = lane & 15;        // MFMA row (A) / col (C/D)
    const int q    = lane >> 4;        // quad
    const int tokbase = blockIdx.x << 6;

    __shared__ float s_bv[4][64];
    __shared__ int   s_bk[4][64];
    __shared__ float s_loss[4];

    // A fragments: 4 tiles x 16 tokens, A[m=lane&15][k=q*8+j], bf16.
    bf16x8 aA[4][2];
    #pragma unroll
    for (int t = 0; t < 4; ++t) {
        const float* rowp = z + (size_t)(tokbase + t * 16 + m) * VQ_D + (q << 3);
        #pragma unroll
        for (int h = 0; h < 2; ++h) {
            const float4* p = (const float4*)(rowp + h * 32);
            float4 x0 = p[0], x1 = p[1];
            bf16x8 v;
            v[0] = bf16rn(x0.x); v[1] = bf16rn(x0.y); v[2] = bf16rn(x0.z); v[3] = bf16rn(x0.w);
            v[4] = bf16rn(x1.x); v[5] = bf16rn(x1.y); v[6] = bf16rn(x1.z); v[7] = bf16rn(x1.w);
            aA[t][h] = v;
        }
    }
    // Pin fragments in VGPRs: sever dataflow to z so the scheduler cannot
    // rematerialize the loads+converts inside the chunk loop (R2/R4 failure).
    #pragma unroll
    for (int t = 0; t < 4; ++t)
        #pragma unroll
        for (int h = 0; h < 2; ++h) asm volatile("" : "+v"(aA[t][h]));

    const bf16x8* cbb = (const bf16x8*)((const char*)ws + WS_CBB_BYTES);
    const float*  csq = ws + WS_CSQ;

    // Running argmin as index-embedded float: low 4 mantissa bits hold the
    // chunk index cc (<=16-ulp perturbation, ~2e-6 relative — noise).
    float bestd[4][4];
    #pragma unroll
    for (int t = 0; t < 4; ++t)
        #pragma unroll
        for (int r = 0; r < 4; ++r) bestd[t][r] = 3.4e38f;

    const int c0 = wave << 4;          // 16 chunks of 16 codes per wave
    bf16x8 b0 = cbb[(c0 * 2 + 0) * 64 + lane];
    bf16x8 b1 = cbb[(c0 * 2 + 1) * 64 + lane];
    float  cs = csq[(c0 << 4) + m];
    for (int cc = 0; cc < 16; ++cc) {
        bf16x8 nb0 = b0, nb1 = b1; float ncs = cs;
        if (cc < 15) {                 // prefetch next chunk (L2-hot)
            const int cn = c0 + cc + 1;
            nb0 = cbb[(cn * 2 + 0) * 64 + lane];
            nb1 = cbb[(cn * 2 + 1) * 64 + lane];
            ncs = csq[(cn << 4) + m];
        }
        #pragma unroll
        for (int t = 0; t < 4; ++t) {
            f32x4 acc = {0.f, 0.f, 0.f, 0.f};
            acc = __builtin_amdgcn_mfma_f32_16x16x32_bf16(aA[t][0], b0, acc, 0, 0, 0);
            acc = __builtin_amdgcn_mfma_f32_16x16x32_bf16(aA[t][1], b1, acc, 0, 0, 0);
            #pragma unroll
            for (int r = 0; r < 4; ++r) {           // C/D: col=m, row=q*4+r
                float dist = cs - 2.0f * acc[r];    // v_fma
                unsigned u = (__builtin_bit_cast(unsigned, dist) & ~15u) | (unsigned)cc;
                float dq = __builtin_bit_cast(float, u);           // v_and_or_b32
                bestd[t][r] = fminf(bestd[t][r], dq);              // v_min_f32
            }
        }
        b0 = nb0; b1 = nb1; cs = ncs;
    }

    // Decode k, cross-lane argmin over the 16 col-lanes (codes interleave
    // across lanes -> (v,k)-lexicographic combine for jnp first-min rule).
    #pragma unroll
    for (int t = 0; t < 4; ++t) {
        #pragma unroll
        for (int r = 0; r < 4; ++r) {
            float v = bestd[t][r];
            int   k = (wave << 8) | ((__builtin_bit_cast(unsigned, v) & 15u) << 4) | m;
            #pragma unroll
            for (int off = 1; off < 16; off <<= 1) {
                float v2 = __shfl_xor(v, off);
                int   k2 = __shfl_xor(k, off);
                if (v2 < v || (v2 == v && k2 < k)) { v = v2; k = k2; }
            }
            if (m == 0) {
                int tok = t * 16 + q * 4 + r;       // token within block
                s_bv[wave][tok] = v; s_bk[wave][tok] = k;
            }
        }
    }
    __syncthreads();

    // Epilogue: thread -> (token, quarter-row). Combine 4 wave-chunks
    // (ascending code ranges), exact fp32 gather + z_q write + loss.
    const int tok = tid >> 2, part = tid & 3;
    float bv = s_bv[0][tok]; int bk = s_bk[0][tok];
    #pragma unroll
    for (int w = 1; w < 4; ++w) {
        float v = s_bv[w][tok]; int k = s_bk[w][tok];
        if (v < bv || (v == bv && k < bk)) { bv = v; bk = k; }
    }
    const float4* crow = (const float4*)(cb + (size_t)bk * VQ_D + part * 16);
    const float4* zrow = (const float4*)(z + (size_t)(tokbase + tok) * VQ_D + part * 16);
    float4*       orow = (float4*)(out + (size_t)(tokbase + tok) * VQ_D + part * 16);
    float lsum = 0.f;
    #pragma unroll
    for (int j = 0; j < 4; ++j) {
        float4 cv = crow[j], zv = zrow[j];
        orow[j] = cv;
        float e0 = zv.x - cv.x, e1 = zv.y - cv.y;
        float e2 = zv.z - cv.z, e3 = zv.w - cv.w;
        lsum += e0 * e0 + e1 * e1 + e2 * e2 + e3 * e3;
    }
    #pragma unroll
    for (int off = 32; off > 0; off >>= 1) lsum += __shfl_down(lsum, off);
    if (lane == 0) s_loss[wave] = lsum;
    __syncthreads();
    if (tid == 0)
        atomicAdd(ws + WS_LOSS, s_loss[0] + s_loss[1] + s_loss[2] + s_loss[3]);
}

__global__ void vq_fin(const float* __restrict__ ws, float* __restrict__ out) {
    if (threadIdx.x == 0 && blockIdx.x == 0) {
        float msq = ws[WS_LOSS] * (1.0f / (float)VQ_NELEM);
        out[VQ_NELEM]     = msq;   // c_loss  (BETA = 1.0)
        out[VQ_NELEM + 1] = msq;   // cb_loss
    }
}

extern "C" void kernel_launch(void* const* d_in, const int* in_sizes, int n_in,
                              void* d_out, int out_size, void* d_ws, size_t ws_size,
                              hipStream_t stream) {
    const float* z  = (const float*)d_in[0];
    const float* cb = (const float*)d_in[1];
    float* out = (float*)d_out;
    float* ws  = (float*)d_ws;

    vq_prep<<<dim3(32), dim3(256), 0, stream>>>(cb, ws);
    vq_mfma<<<dim3(VQ_NTOK / 64), dim3(256), 0, stream>>>(z, cb, ws, out);
    vq_fin<<<dim3(1), dim3(64), 0, stream>>>(ws, out);
}